// Round 8
// baseline (658.679 us; speedup 1.0000x reference)
//
#include <hip/hip_runtime.h>
#include <math.h>

#define NN 50000
#define NF 512
#define NHID 256
#define NCLASS 64
#define NHEADS 8

typedef __attribute__((ext_vector_type(8))) short bf16x8;
typedef __attribute__((ext_vector_type(4))) float f32x4;

static __device__ __forceinline__ unsigned short f2bf(float f) {
  unsigned int u = __float_as_uint(f);
  unsigned int r = (u + 0x7fffu + ((u >> 16) & 1u)) >> 16;
  return (unsigned short)r;
}
static __device__ __forceinline__ float bf2f(unsigned short u) {
  return __uint_as_float(((unsigned int)u) << 16);
}
static __device__ __forceinline__ float2 bfpair(unsigned int u) {
  return make_float2(__uint_as_float(u << 16), __uint_as_float(u & 0xffff0000u));
}

// ---------------- CSR build ----------------
__global__ void k_init_deg(int* deg) {
  int i = blockIdx.x * blockDim.x + threadIdx.x;
  if (i < NN) deg[i] = 1;  // self loop
}

__global__ void k_count(const int* __restrict__ dst, int E0, int* deg) {
  int i = blockIdx.x * blockDim.x + threadIdx.x;
  if (i < E0) atomicAdd(&deg[dst[i]], 1);
}

__global__ __launch_bounds__(1024) void k_scan(const int* __restrict__ deg, int* offs,
                                               int* cursor) {
  __shared__ int wbase[16];
  __shared__ int srun;
  int tid = threadIdx.x;
  int lane = tid & 63;
  int wv = tid >> 6;
  if (tid == 0) srun = 0;
  __syncthreads();
  for (int base = 0; base < NN; base += 4096) {
    int i = base + tid * 4;
    int4 v;
    if (i + 3 < NN) {
      v = *(const int4*)(deg + i);
    } else {
      v.x = (i + 0 < NN) ? deg[i + 0] : 0;
      v.y = (i + 1 < NN) ? deg[i + 1] : 0;
      v.z = (i + 2 < NN) ? deg[i + 2] : 0;
      v.w = (i + 3 < NN) ? deg[i + 3] : 0;
    }
    int tot = v.x + v.y + v.z + v.w;
    int s = tot;
    #pragma unroll
    for (int o = 1; o < 64; o <<= 1) {
      int t = __shfl_up(s, o);
      if (lane >= o) s += t;
    }
    if (lane == 63) wbase[wv] = s;
    __syncthreads();
    if (tid == 0) {
      int run = srun;
      #pragma unroll
      for (int w2 = 0; w2 < 16; w2++) {
        int t = wbase[w2];
        wbase[w2] = run;
        run += t;
      }
      srun = run;
    }
    __syncthreads();
    int p = wbase[wv] + s - tot;
    if (i + 0 < NN) { offs[i + 0] = p; cursor[i + 0] = p; p += v.x; }
    if (i + 1 < NN) { offs[i + 1] = p; cursor[i + 1] = p; p += v.y; }
    if (i + 2 < NN) { offs[i + 2] = p; cursor[i + 2] = p; p += v.z; }
    if (i + 3 < NN) { offs[i + 3] = p; cursor[i + 3] = p; }
  }
  __syncthreads();
  if (tid == 0) offs[NN] = srun;
}

__global__ void k_scatter(const int* __restrict__ src, const int* __restrict__ dst,
                          int E0, int* cursor, int* __restrict__ nbr) {
  int i = blockIdx.x * blockDim.x + threadIdx.x;
  if (i < E0) {
    int pos = atomicAdd(&cursor[dst[i]], 1);
    nbr[pos] = src[i];
  } else if (i < E0 + NN) {
    int v = i - E0;
    int pos = atomicAdd(&cursor[v], 1);
    nbr[pos] = v;
  }
}

// ---------------- casts ----------------
__global__ void k_cast4(const float* __restrict__ in, unsigned short* __restrict__ out,
                        int n4) {
  int i = blockIdx.x * blockDim.x + threadIdx.x;
  if (i >= n4) return;
  float4 v = *(const float4*)(in + (size_t)i * 4);
  ushort4 o;
  o.x = f2bf(v.x); o.y = f2bf(v.y); o.z = f2bf(v.z); o.w = f2bf(v.w);
  *(ushort4*)(out + (size_t)i * 4) = o;
}

__global__ void k_castWt(const float* __restrict__ W, unsigned short* __restrict__ Wt,
                         int K, int cols) {
  int i = blockIdx.x * blockDim.x + threadIdx.x;
  if (i >= K * cols) return;
  int k = i / cols, c = i % cols;
  Wt[(size_t)c * K + k] = f2bf(W[i]);
}

__global__ void k_castWt_perm(const float* __restrict__ W, unsigned short* __restrict__ Wt,
                              int K) {
  int i = blockIdx.x * blockDim.x + threadIdx.x;
  if (i >= K * NHEADS * NCLASS) return;
  int k = i / (NHEADS * NCLASS);
  int rem = i % (NHEADS * NCLASS);
  int h = rem / NCLASS, c = rem % NCLASS;
  Wt[(size_t)(c * NHEADS + h) * K + k] = f2bf(W[i]);
}

// ---------------- bf16 MFMA GEMM, LDS-staged B, bf16 output ----------------
__global__ __launch_bounds__(256) void k_gemm_bf(const unsigned short* __restrict__ A,
                                                 const unsigned short* __restrict__ Bt,
                                                 unsigned short* __restrict__ C,
                                                 int rows, int K, int cols) {
  __shared__ unsigned short Bs[256 * 40];  // 20 KB
  int t = threadIdx.x;
  int wave = t >> 6, lane = t & 63;
  int quad = lane >> 4, sixt = lane & 15;
  int rb = blockIdx.x * 64 + (wave >> 1) * 32;
  int cw = (wave & 1) * 128;
  int cbw = blockIdx.y * 256 + cw;
  int r0 = rb + sixt, r1 = rb + 16 + sixt;
  const unsigned short* Ap0 = A + (size_t)(r0 < rows ? r0 : 0) * K + quad * 8;
  const unsigned short* Ap1 = A + (size_t)(r1 < rows ? r1 : 0) * K + quad * 8;
  const unsigned short* Bg = Bt + (size_t)(blockIdx.y * 256 + (t >> 2)) * K + (t & 3) * 8;
  const size_t BgStep = (size_t)64 * K;
  char* BsW = (char*)Bs + (t >> 2) * 80 + (t & 3) * 16;
  f32x4 acc0[8] = {}, acc1[8] = {};
  for (int k0 = 0; k0 < K; k0 += 32) {
    uint4 v0 = *(const uint4*)(Bg + k0);
    uint4 v1 = *(const uint4*)(Bg + BgStep + k0);
    uint4 v2 = *(const uint4*)(Bg + 2 * BgStep + k0);
    uint4 v3 = *(const uint4*)(Bg + 3 * BgStep + k0);
    bf16x8 a0 = *(const bf16x8*)(Ap0 + k0);
    bf16x8 a1 = *(const bf16x8*)(Ap1 + k0);
    *(uint4*)(BsW) = v0;
    *(uint4*)(BsW + 64 * 80) = v1;
    *(uint4*)(BsW + 128 * 80) = v2;
    *(uint4*)(BsW + 192 * 80) = v3;
    __syncthreads();
    #pragma unroll
    for (int g = 0; g < 8; g++) {
      bf16x8 b = *(const bf16x8*)((const char*)Bs + (cw + g * 16 + sixt) * 80 + quad * 16);
      acc0[g] = __builtin_amdgcn_mfma_f32_16x16x32_bf16(a0, b, acc0[g], 0, 0, 0);
      acc1[g] = __builtin_amdgcn_mfma_f32_16x16x32_bf16(a1, b, acc1[g], 0, 0, 0);
    }
    __syncthreads();
  }
  #pragma unroll
  for (int r = 0; r < 4; r++) {
    int row = rb + quad * 4 + r;
    if (row < rows) {
      unsigned short* out = C + (size_t)row * cols + cbw + sixt;
      #pragma unroll
      for (int g = 0; g < 8; g++) out[g * 16] = f2bf(acc0[g][r]);
    }
    int row2 = row + 16;
    if (row2 < rows) {
      unsigned short* out = C + (size_t)row2 * cols + cbw + sixt;
      #pragma unroll
      for (int g = 0; g < 8; g++) out[g * 16] = f2bf(acc1[g][r]);
    }
  }
}

// ---------------- edge-score dots, contiguous layout (layer 1) ----------------
template <int C>
__global__ void k_escore_c(const unsigned short* __restrict__ h,
                           const float* __restrict__ asr, const float* __restrict__ ads,
                           float* __restrict__ es, float* __restrict__ ed) {
  int idx = blockIdx.x * blockDim.x + threadIdx.x;  // n*8 + head
  if (idx >= NN * NHEADS) return;
  int hd = idx & 7;
  const unsigned short* row = h + (size_t)idx * C;
  float s = 0.f, d = 0.f;
  #pragma unroll
  for (int c8 = 0; c8 < C / 8; c8++) {
    uint4 raw = *(const uint4*)(row + c8 * 8);
    float2 p0 = bfpair(raw.x), p1 = bfpair(raw.y), p2 = bfpair(raw.z), p3 = bfpair(raw.w);
    const float* as_ = asr + hd * C + c8 * 8;
    const float* ad_ = ads + hd * C + c8 * 8;
    s += p0.x * as_[0] + p0.y * as_[1] + p1.x * as_[2] + p1.y * as_[3] +
         p2.x * as_[4] + p2.y * as_[5] + p3.x * as_[6] + p3.y * as_[7];
    d += p0.x * ad_[0] + p0.y * ad_[1] + p1.x * ad_[2] + p1.y * ad_[3] +
         p2.x * ad_[4] + p2.y * ad_[5] + p3.x * ad_[6] + p3.y * ad_[7];
  }
  es[idx] = s;
  ed[idx] = d;
}

// ---------------- edge-score dots, permuted layout (layer 2), wave/node ----------
// h [n][c*8 + h] bf16. Lane = class: one uint4 covers all 8 heads of class lane.
// s[h] = sum_c v[c][h]*a[h][c] via per-lane FMA + 6-level butterfly.
__global__ __launch_bounds__(256) void k_escore_p(const unsigned short* __restrict__ h,
                                                  const float* __restrict__ asr,
                                                  const float* __restrict__ ads,
                                                  float* __restrict__ es,
                                                  float* __restrict__ ed) {
  int node = blockIdx.x * 4 + (threadIdx.x >> 6);
  if (node >= NN) return;
  int lane = threadIdx.x & 63;  // class
  uint4 r = *(const uint4*)(h + (size_t)node * (NHEADS * NCLASS) + (lane << 3));
  float2 p0 = bfpair(r.x), p1 = bfpair(r.y), p2 = bfpair(r.z), p3 = bfpair(r.w);
  float v[8] = {p0.x, p0.y, p1.x, p1.y, p2.x, p2.y, p3.x, p3.y};
  float s[8], d[8];
  #pragma unroll
  for (int j = 0; j < 8; j++) {
    s[j] = v[j] * asr[j * NCLASS + lane];
    d[j] = v[j] * ads[j * NCLASS + lane];
  }
  #pragma unroll
  for (int o = 1; o < 64; o <<= 1) {
    #pragma unroll
    for (int j = 0; j < 8; j++) {
      s[j] += __shfl_xor(s[j], o);
      d[j] += __shfl_xor(d[j], o);
    }
  }
  if (lane < 8) {
    float so = s[0], dd = d[0];
    #pragma unroll
    for (int j = 1; j < 8; j++) {
      if (lane == j) { so = s[j]; dd = d[j]; }
    }
    es[node * NHEADS + lane] = so;
    ed[node * NHEADS + lane] = dd;
  }
}

// ---------------- fused softmax + layer-1 aggregation ----------------
__global__ __launch_bounds__(256) void k_agg1f(const int* __restrict__ offs,
                                               const int* __restrict__ nbr,
                                               const unsigned short* __restrict__ h1,
                                               const float* __restrict__ es,
                                               const float* __restrict__ ed,
                                               const float* __restrict__ b1,
                                               unsigned short* __restrict__ out) {
  int node = blockIdx.x * 4 + (threadIdx.x >> 6);
  if (node >= NN) return;
  int lane = threadIdx.x & 63;
  int h = lane & 7;
  int beg = offs[node], end = offs[node + 1];
  float edst = ed[node * NHEADS + h];
  float m = -1e30f, z = 0.f;
  for (int k = beg + (lane >> 3); k < end; k += 8) {
    int s = nbr[k];
    float a = es[s * NHEADS + h] + edst;
    a = (a > 0.f) ? a : 0.2f * a;
    float mn = fmaxf(m, a);
    z = z * __expf(m - mn) + __expf(a - mn);
    m = mn;
  }
  #pragma unroll
  for (int o = 8; o < 64; o <<= 1) {
    float m2 = __shfl_xor(m, o);
    float z2 = __shfl_xor(z, o);
    float mn = fmaxf(m, m2);
    z = z * __expf(m - mn) + z2 * __expf(m2 - mn);
    m = mn;
  }
  float inv = 1.f / z;
  int head = lane >> 3;
  float mh = __shfl(m, head);
  float ivh = __shfl(inv, head);
  float edh = __shfl(edst, head);
  float4 acc = make_float4(0.f, 0.f, 0.f, 0.f);
  int k = beg;
  for (; k + 1 < end; k += 2) {
    int s0 = nbr[k], s1 = nbr[k + 1];
    float a0 = es[s0 * NHEADS + head] + edh;
    float a1c = es[s1 * NHEADS + head] + edh;
    a0 = (a0 > 0.f) ? a0 : 0.2f * a0;
    a1c = (a1c > 0.f) ? a1c : 0.2f * a1c;
    float c0 = __expf(a0 - mh) * ivh;
    float c1 = __expf(a1c - mh) * ivh;
    uint2 r0 = *(const uint2*)(h1 + (size_t)s0 * NHID + (lane << 2));
    uint2 r1 = *(const uint2*)(h1 + (size_t)s1 * NHID + (lane << 2));
    float2 p0 = bfpair(r0.x), p1 = bfpair(r0.y);
    float2 q0 = bfpair(r1.x), q1 = bfpair(r1.y);
    acc.x += c0 * p0.x + c1 * q0.x;
    acc.y += c0 * p0.y + c1 * q0.y;
    acc.z += c0 * p1.x + c1 * q1.x;
    acc.w += c0 * p1.y + c1 * q1.y;
  }
  if (k < end) {
    int s0 = nbr[k];
    float a0 = es[s0 * NHEADS + head] + edh;
    a0 = (a0 > 0.f) ? a0 : 0.2f * a0;
    float c0 = __expf(a0 - mh) * ivh;
    uint2 r0 = *(const uint2*)(h1 + (size_t)s0 * NHID + (lane << 2));
    float2 p0 = bfpair(r0.x), p1 = bfpair(r0.y);
    acc.x += c0 * p0.x;
    acc.y += c0 * p0.y;
    acc.z += c0 * p1.x;
    acc.w += c0 * p1.y;
  }
  int col = lane << 2;
  ushort4 o;
  o.x = f2bf(fmaxf(acc.x + b1[col + 0], 0.f));
  o.y = f2bf(fmaxf(acc.y + b1[col + 1], 0.f));
  o.z = f2bf(fmaxf(acc.z + b1[col + 2], 0.f));
  o.w = f2bf(fmaxf(acc.w + b1[col + 3], 0.f));
  *(ushort4*)(out + (size_t)node * NHID + col) = o;
}

// ---------------- fused softmax + layer-2 aggregation + mean + log_softmax ----------
// Sweep 2: 16-edge chunks (2 staging iters per LDS wait), gather 4-edge unrolled.
__global__ __launch_bounds__(256) void k_agg2f(const int* __restrict__ offs,
                                               const int* __restrict__ nbr,
                                               const unsigned short* __restrict__ h2,
                                               const float* __restrict__ es,
                                               const float* __restrict__ ed,
                                               const float* __restrict__ b2,
                                               float* __restrict__ out) {
  __shared__ float cs[4][128];  // per wave: 16 edges x 8 heads
  int wv = threadIdx.x >> 6;
  int node = blockIdx.x * 4 + wv;
  if (node >= NN) return;
  int lane = threadIdx.x & 63;
  int h = lane & 7;
  int sub = lane >> 3;
  int beg = offs[node], end = offs[node + 1];
  float edst = ed[node * NHEADS + h];
  float m = -1e30f, z = 0.f;
  for (int k = beg + sub; k < end; k += 8) {
    int s = nbr[k];
    float a = es[s * NHEADS + h] + edst;
    a = (a > 0.f) ? a : 0.2f * a;
    float mn = fmaxf(m, a);
    z = z * __expf(m - mn) + __expf(a - mn);
    m = mn;
  }
  #pragma unroll
  for (int o = 8; o < 64; o <<= 1) {
    float m2 = __shfl_xor(m, o);
    float z2 = __shfl_xor(z, o);
    float mn = fmaxf(m, m2);
    z = z * __expf(m - mn) + z2 * __expf(m2 - mn);
    m = mn;
  }
  float inv = 1.f / z;
  float acc[8] = {};
  for (int kb = beg; kb < end; kb += 16) {
    int cnt = end - kb;
    if (cnt > 16) cnt = 16;
    // stage 16 edges' coefs: 2 iterations, one LDS wait amortized over 16 gathers
    #pragma unroll
    for (int it = 0; it < 2; it++) {
      int ki = kb + it * 8 + sub;
      int s = nbr[ki < end ? ki : end - 1];
      float a = es[s * NHEADS + h] + edst;
      a = (a > 0.f) ? a : 0.2f * a;
      float c = __expf(a - m) * inv;
      cs[wv][(it * 8 + sub) * 8 + h] = (ki < end) ? c : 0.f;
    }
    int e = 0;
    for (; e + 3 < cnt; e += 4) {
      int s0 = nbr[kb + e], s1 = nbr[kb + e + 1];
      int s2 = nbr[kb + e + 2], s3 = nbr[kb + e + 3];
      uint4 r0 = *(const uint4*)(h2 + (size_t)s0 * (NHEADS * NCLASS) + (lane << 3));
      uint4 r1 = *(const uint4*)(h2 + (size_t)s1 * (NHEADS * NCLASS) + (lane << 3));
      uint4 r2 = *(const uint4*)(h2 + (size_t)s2 * (NHEADS * NCLASS) + (lane << 3));
      uint4 r3 = *(const uint4*)(h2 + (size_t)s3 * (NHEADS * NCLASS) + (lane << 3));
      {
        float4 cA = *(const float4*)&cs[wv][(e + 0) * 8];
        float4 cB = *(const float4*)&cs[wv][(e + 0) * 8 + 4];
        float2 p0 = bfpair(r0.x), p1 = bfpair(r0.y), p2 = bfpair(r0.z), p3 = bfpair(r0.w);
        acc[0] += cA.x * p0.x; acc[1] += cA.y * p0.y;
        acc[2] += cA.z * p1.x; acc[3] += cA.w * p1.y;
        acc[4] += cB.x * p2.x; acc[5] += cB.y * p2.y;
        acc[6] += cB.z * p3.x; acc[7] += cB.w * p3.y;
      }
      {
        float4 cA = *(const float4*)&cs[wv][(e + 1) * 8];
        float4 cB = *(const float4*)&cs[wv][(e + 1) * 8 + 4];
        float2 p0 = bfpair(r1.x), p1 = bfpair(r1.y), p2 = bfpair(r1.z), p3 = bfpair(r1.w);
        acc[0] += cA.x * p0.x; acc[1] += cA.y * p0.y;
        acc[2] += cA.z * p1.x; acc[3] += cA.w * p1.y;
        acc[4] += cB.x * p2.x; acc[5] += cB.y * p2.y;
        acc[6] += cB.z * p3.x; acc[7] += cB.w * p3.y;
      }
      {
        float4 cA = *(const float4*)&cs[wv][(e + 2) * 8];
        float4 cB = *(const float4*)&cs[wv][(e + 2) * 8 + 4];
        float2 p0 = bfpair(r2.x), p1 = bfpair(r2.y), p2 = bfpair(r2.z), p3 = bfpair(r2.w);
        acc[0] += cA.x * p0.x; acc[1] += cA.y * p0.y;
        acc[2] += cA.z * p1.x; acc[3] += cA.w * p1.y;
        acc[4] += cB.x * p2.x; acc[5] += cB.y * p2.y;
        acc[6] += cB.z * p3.x; acc[7] += cB.w * p3.y;
      }
      {
        float4 cA = *(const float4*)&cs[wv][(e + 3) * 8];
        float4 cB = *(const float4*)&cs[wv][(e + 3) * 8 + 4];
        float2 p0 = bfpair(r3.x), p1 = bfpair(r3.y), p2 = bfpair(r3.z), p3 = bfpair(r3.w);
        acc[0] += cA.x * p0.x; acc[1] += cA.y * p0.y;
        acc[2] += cA.z * p1.x; acc[3] += cA.w * p1.y;
        acc[4] += cB.x * p2.x; acc[5] += cB.y * p2.y;
        acc[6] += cB.z * p3.x; acc[7] += cB.w * p3.y;
      }
    }
    for (; e < cnt; e++) {
      int se = nbr[kb + e];
      float4 cA = *(const float4*)&cs[wv][e * 8];
      float4 cB = *(const float4*)&cs[wv][e * 8 + 4];
      uint4 r = *(const uint4*)(h2 + (size_t)se * (NHEADS * NCLASS) + (lane << 3));
      float2 p0 = bfpair(r.x), p1 = bfpair(r.y), p2 = bfpair(r.z), p3 = bfpair(r.w);
      acc[0] += cA.x * p0.x; acc[1] += cA.y * p0.y;
      acc[2] += cA.z * p1.x; acc[3] += cA.w * p1.y;
      acc[4] += cB.x * p2.x; acc[5] += cB.y * p2.y;
      acc[6] += cB.z * p3.x; acc[7] += cB.w * p3.y;
    }
  }
  float val = 0.f;
  #pragma unroll
  for (int hh = 0; hh < 8; hh++) val += acc[hh];
  val = val * 0.125f + b2[lane];
  float mx = val;
  #pragma unroll
  for (int o = 32; o > 0; o >>= 1) mx = fmaxf(mx, __shfl_xor(mx, o));
  float ex = __expf(val - mx);
  float sm = ex;
  #pragma unroll
  for (int o = 32; o > 0; o >>= 1) sm += __shfl_xor(sm, o);
  out[(size_t)node * NCLASS + lane] = val - mx - __logf(sm);
}

// ---------------- launch ----------------
extern "C" void kernel_launch(void* const* d_in, const int* in_sizes, int n_in,
                              void* d_out, int out_size, void* d_ws, size_t ws_size,
                              hipStream_t stream) {
  const float* x   = (const float*)d_in[0];
  const int* eidx  = (const int*)d_in[1];
  const float* W1  = (const float*)d_in[2];
  const float* a1s = (const float*)d_in[3];
  const float* a1d = (const float*)d_in[4];
  const float* b1  = (const float*)d_in[5];
  const float* W2  = (const float*)d_in[6];
  const float* a2s = (const float*)d_in[7];
  const float* a2d = (const float*)d_in[8];
  const float* b2  = (const float*)d_in[9];
  const int E0 = in_sizes[1] / 2;
  const int* esrc = eidx;
  const int* edst = eidx + E0;
  const int E = E0 + NN;

  char* w = (char*)d_ws;
  auto carve = [&](size_t bytes) {
    void* p = (void*)w;
    w += (bytes + 255) & ~(size_t)255;
    return p;
  };
  int* deg      = (int*)carve((size_t)NN * 4);
  int* offs     = (int*)carve((size_t)(NN + 1) * 4);
  int* cursor   = (int*)carve((size_t)NN * 4);
  int* nbr      = (int*)carve((size_t)E * 4);
  float* es1    = (float*)carve((size_t)NN * NHEADS * 4);
  float* ed1    = (float*)carve((size_t)NN * NHEADS * 4);
  unsigned short* xbf   = (unsigned short*)carve((size_t)NN * NF * 2);
  unsigned short* W1t   = (unsigned short*)carve((size_t)NF * NHID * 2);
  unsigned short* W2t   = (unsigned short*)carve((size_t)NHID * NHEADS * NCLASS * 2);
  unsigned short* h1b   = (unsigned short*)carve((size_t)NN * NHID * 2);
  unsigned short* out1b = (unsigned short*)carve((size_t)NN * NHID * 2);
  unsigned short* h2b   = (unsigned short*)carve((size_t)NN * NHEADS * NCLASS * 2);

  // CSR build
  k_init_deg<<<(NN + 255) / 256, 256, 0, stream>>>(deg);
  k_count<<<(E0 + 255) / 256, 256, 0, stream>>>(edst, E0, deg);
  k_scan<<<1, 1024, 0, stream>>>(deg, offs, cursor);
  k_scatter<<<(E0 + NN + 255) / 256, 256, 0, stream>>>(esrc, edst, E0, cursor, nbr);

  // casts
  k_cast4<<<(NN * NF / 4 + 255) / 256, 256, 0, stream>>>(x, xbf, NN * NF / 4);
  k_castWt<<<(NF * NHID + 255) / 256, 256, 0, stream>>>(W1, W1t, NF, NHID);
  k_castWt_perm<<<(NHID * NHEADS * NCLASS + 255) / 256, 256, 0, stream>>>(W2, W2t, NHID);

  // layer 1
  k_gemm_bf<<<dim3((NN + 63) / 64, NHID / 256), 256, 0, stream>>>(xbf, W1t, h1b,
                                                                  NN, NF, NHID);
  k_escore_c<32><<<(NN * NHEADS + 255) / 256, 256, 0, stream>>>(h1b, a1s, a1d, es1, ed1);
  k_agg1f<<<(NN + 3) / 4, 256, 0, stream>>>(offs, nbr, h1b, es1, ed1, b1, out1b);

  // layer 2
  k_gemm_bf<<<dim3((NN + 63) / 64, (NHEADS * NCLASS) / 256), 256, 0, stream>>>(
      out1b, W2t, h2b, NN, NHID, NHEADS * NCLASS);
  k_escore_p<<<(NN + 3) / 4, 256, 0, stream>>>(h2b, a2s, a2d, es1, ed1);
  k_agg2f<<<(NN + 3) / 4, 256, 0, stream>>>(offs, nbr, h2b, es1, ed1, b2, (float*)d_out);
}